// Round 17
// baseline (177.539 us; speedup 1.0000x reference)
//
#include <hip/hip_runtime.h>
#include <math.h>

// ExplaiNN fused forward: B=128, N=300, L=600, K=19, C1=100, PS=7
// LC=582, LP=83, NC=2
#define EPS_ 1e-5f

// ---------------------------------------------------------------------------
// kP: cw4[c][kq][n][0..3] float4 conv-weight pack for kA (20 blocks, ~2us).
// ---------------------------------------------------------------------------
__global__ __launch_bounds__(256) void kP(const float* __restrict__ conv_w,
                                          float* __restrict__ cw4) {
    const int cq = blockIdx.x;              // 0..19
    const int c  = cq / 5;
    const int kq = cq - c * 5;
    for (int n = threadIdx.x; n < 300; n += 256) {
        float4 v;
        const int k0 = 4 * kq;
        v.x = (k0 + 0 < 19) ? conv_w[n * 76 + c * 19 + k0 + 0] : 0.f;
        v.y = (k0 + 1 < 19) ? conv_w[n * 76 + c * 19 + k0 + 1] : 0.f;
        v.z = (k0 + 2 < 19) ? conv_w[n * 76 + c * 19 + k0 + 2] : 0.f;
        v.w = (k0 + 3 < 19) ? conv_w[n * 76 + c * 19 + k0 + 3] : 0.f;
        reinterpret_cast<float4*>(cw4)[(c * 5 + kq) * 300 + n] = v;
    }
}

// ---------------------------------------------------------------------------
// kA: conv1d(4ch,K=19) + bias + bn1 + exp + maxpool(7,7).  R9 instruction
// stream (best: 44-47us, VGPR=32) + L1-LOCALITY SUB REMAP: a CU's resident
// block ids differ by multiples of 256 -> sub%16 is CU-invariant. Encoding
// sub = u*16 + r (r<15 active), ng = r%5, pc = u*3 + r/5 pins ONE ng per CU
// -> its 19.4KB cw4 slice L1-resident -> weight loads ~30cy instead of
// ~200cy L2 (the measured 42% stall). XCD line assembly preserved: b-stride
// 112 == 0 mod 8; sub<->(ng,pc) bijection keeps same-sub-same-XCD. Cost:
// r=15 dead (~6% CUs idle). Instruction stream identical to R9.
// ---------------------------------------------------------------------------
__global__ __launch_bounds__(64) void kA(
        const float* __restrict__ x,        // [128][4][600]
        const float* __restrict__ cw4,      // [4][5][300][4]
        const float* __restrict__ conv_b,
        const float* __restrict__ g1, const float* __restrict__ b1,
        const float* __restrict__ m1, const float* __restrict__ v1,
        float* __restrict__ pooled)         // [300][83][128]
{
    const int id  = blockIdx.x;             // b*112 + sub
    const int b   = id / 112;
    const int sub = id - b * 112;
    const int u   = sub >> 4;               // 0..6
    const int r   = sub & 15;               // 0..15
    if (r >= 15) return;                    // 7 dead subs (CU-aligned)
    const int ng  = r % 5;
    const int pc  = u * 3 + r / 5;          // 0..20
    const int p0c = pc * 4;
    const int p0  = (p0c > 79) ? 79 : p0c;  // p=79 done twice, same value
    const int lane = threadIdx.x;
    const int n   = ng * 64 + lane;
    const int nc  = (n < 300) ? n : 299;

    const float4* w4 = reinterpret_cast<const float4*>(cw4);

    float acc[28];
    #pragma unroll
    for (int i = 0; i < 28; ++i) acc[i] = 0.f;

    #pragma unroll 1
    for (int c = 0; c < 4; ++c) {
        const float* xc = x + b * 2400 + c * 600 + 7 * p0;  // uniform -> s_load
        float xw[46];
        #pragma unroll
        for (int j = 0; j < 46; ++j) xw[j] = xc[j];
        #pragma unroll
        for (int kq = 0; kq < 5; ++kq) {
            const float4 wv = w4[(c * 5 + kq) * 300 + nc];  // L1-hot now
            const int ni = (kq == 4) ? 3 : 4;               // k<19
            #pragma unroll
            for (int i = 0; i < ni; ++i) {
                const int k = 4 * kq + i;
                const float wvv = (i == 0) ? wv.x : (i == 1) ? wv.y
                                : (i == 2) ? wv.z : wv.w;
                #pragma unroll
                for (int p = 0; p < 4; ++p)
                    #pragma unroll
                    for (int q = 0; q < 7; ++q)
                        acc[p * 7 + q] = fmaf(xw[7 * p + q + k], wvv,
                                              acc[p * 7 + q]);
            }
        }
    }

    const float A1 = g1[nc] * rsqrtf(v1[nc] + EPS_);
    const float B1 = fmaf(A1, conv_b[nc] - m1[nc], b1[nc]);
    if (n < 300) {
        float* op = pooled + ((size_t)n * 83 + p0) * 128 + b;
        #pragma unroll
        for (int p = 0; p < 4; ++p) {
            float mx = -INFINITY;           // exp monotone: max before exp
            #pragma unroll
            for (int q = 0; q < 7; ++q)
                mx = fmaxf(mx, fmaf(A1, acc[p * 7 + q], B1));
            op[p * 128] = __expf(mx);
        }
    }
}

// ---------------------------------------------------------------------------
// kB: fc1(K=83) + bn2 + relu + fc2 partial.  UNCHANGED from R16 (passed,
// below top-5 cutoff): block = (n, b-half, h-half), grid 1200 x 256 ->
// 4.7 waves/SIMD; sW[83][60] staging (8-way writes ~free, broadcast reads
// conflict-free); fc2 partials to sp; kC absorbs fc2b+bn3+relu.
// ---------------------------------------------------------------------------
__global__ __launch_bounds__(256) void kB(
        const float* __restrict__ pooled,   // [300][83][128]
        const float* __restrict__ fc1w,     // [300][100][83]
        const float* __restrict__ fc1b,     // [300][100]
        const float* __restrict__ g2, const float* __restrict__ b2,
        const float* __restrict__ m2, const float* __restrict__ v2,
        const float* __restrict__ fc2w,     // [300][100]
        float* __restrict__ sp)             // [2][300][128] fc2 partials
{
    __shared__ float sW[83 * 60];           // 19.9 KB
    __shared__ float sRed[4][64];
    const int id  = blockIdx.x;             // 0..1199
    const int n   = id >> 2;
    const int rem = id & 3;
    const int bh  = rem >> 1;
    const int hq  = rem & 1;                // h-half: h in [hq*50, hq*50+50)
    const int tid = threadIdx.x;

    {   // stage this h-half: coalesced reads; stride-60 writes (8-way, ~free)
        const float* src = fc1w + (size_t)n * 8300 + hq * 50 * 83;
        for (int i = tid; i < 4150; i += 256) {
            const int h = i / 83, p = i - h * 83;
            sW[p * 60 + h] = src[i];
        }
        for (int i = tid; i < 830; i += 256) {   // zero pad h'=50..59
            const int p = i / 10, h = 50 + (i - p * 10);
            sW[p * 60 + h] = 0.f;
        }
    }
    __syncthreads();

    const int lane = tid & 63;
    const int wv   = __builtin_amdgcn_readfirstlane(tid >> 6);  // 0..3
    const int h0   = wv * 13;               // local: 0,13,26,39
    const int nh   = (wv < 3) ? 13 : 11;    // 13*3+11 = 50
    const int bb   = bh * 64 + lane;

    const float* pp = pooled + (size_t)n * 83 * 128 + bb;

    float acc[13];
    #pragma unroll
    for (int j = 0; j < 13; ++j) acc[j] = 0.f;

    #pragma unroll 4
    for (int p = 0; p < 83; ++p) {
        const float pv = pp[p * 128];       // coalesced 256B
        const float* wrow = sW + p * 60 + h0;
        #pragma unroll
        for (int j = 0; j < 13; ++j)        // broadcast b32 reads
            acc[j] = fmaf(wrow[j], pv, acc[j]);
    }

    // bn2 + relu + fc2 partial over this wave's real h's (params uniform)
    const int hbase = n * 100 + hq * 50 + h0;
    float part = 0.f;
    for (int j = 0; j < nh; ++j) {
        const int hi = hbase + j;
        const float A2 = g2[hi] * rsqrtf(v2[hi] + EPS_);
        const float C2 = fmaf(A2, fc1b[hi] - m2[hi], b2[hi]);
        part = fmaf(fmaxf(fmaf(A2, acc[j], C2), 0.f), fc2w[hi], part);
    }
    sRed[wv][lane] = part;
    __syncthreads();

    if (tid < 64) {
        const float s = sRed[0][tid] + sRed[1][tid] + sRed[2][tid] + sRed[3][tid];
        sp[((size_t)hq * 300 + n) * 128 + bh * 64 + tid] = s;
    }
}

// ---------------------------------------------------------------------------
// kC: combine fc2 partials + fc2b + bn3 + relu, then final [300]x[2] matmul.
// ---------------------------------------------------------------------------
__global__ __launch_bounds__(64) void kC(
        const float* __restrict__ sp,       // [2][300][128]
        const float* __restrict__ fc2b,
        const float* __restrict__ g3, const float* __restrict__ b3,
        const float* __restrict__ m3, const float* __restrict__ v3,
        const float* __restrict__ fw,       // [2][300]
        const float* __restrict__ fb,
        float* __restrict__ out)            // [128][2]
{
    const int b = blockIdx.x, t = threadIdx.x;
    float a0 = 0.f, a1 = 0.f;
    for (int nn = t; nn < 300; nn += 64) {
        const float s = sp[nn * 128 + b] + sp[(300 + nn) * 128 + b] + fc2b[nn];
        const float A3 = g3[nn] * rsqrtf(v3[nn] + EPS_);
        const float z = fmaxf(fmaf(A3, s - m3[nn], b3[nn]), 0.f);
        a0 = fmaf(z, fw[nn], a0);
        a1 = fmaf(z, fw[300 + nn], a1);
    }
    #pragma unroll
    for (int off = 32; off > 0; off >>= 1) {
        a0 += __shfl_xor(a0, off, 64);
        a1 += __shfl_xor(a1, off, 64);
    }
    if (t == 0) {
        out[b * 2 + 0] = a0 + fb[0];
        out[b * 2 + 1] = a1 + fb[1];
    }
}

extern "C" void kernel_launch(void* const* d_in, const int* in_sizes, int n_in,
                              void* d_out, int out_size, void* d_ws, size_t ws_size,
                              hipStream_t stream) {
    const float* x      = (const float*)d_in[0];
    const float* conv_w = (const float*)d_in[1];
    const float* conv_b = (const float*)d_in[2];
    const float* g1 = (const float*)d_in[3];
    const float* b1 = (const float*)d_in[4];
    const float* m1 = (const float*)d_in[5];
    const float* v1 = (const float*)d_in[6];
    const float* fc1_w = (const float*)d_in[7];
    const float* fc1_b = (const float*)d_in[8];
    const float* g2 = (const float*)d_in[9];
    const float* b2 = (const float*)d_in[10];
    const float* m2 = (const float*)d_in[11];
    const float* v2 = (const float*)d_in[12];
    const float* fc2_w = (const float*)d_in[13];
    const float* fc2_b = (const float*)d_in[14];
    const float* g3 = (const float*)d_in[15];
    const float* b3 = (const float*)d_in[16];
    const float* m3 = (const float*)d_in[17];
    const float* v3 = (const float*)d_in[18];
    const float* fw = (const float*)d_in[19];
    const float* fb = (const float*)d_in[20];
    float* out = (float*)d_out;

    float* pooled = (float*)d_ws;                        // 300*83*128 = 3187200
    float* sp     = pooled + (size_t)300 * 83 * 128;     // 2*300*128  = 76800
    float* cw4    = sp + 76800;                          // 4*5*300*4  = 24000
    // total ws: ~13.2 MB

    kP<<<20, 256, 0, stream>>>(conv_w, cw4);
    kA<<<128 * 112, 64, 0, stream>>>(x, cw4, conv_b, g1, b1, m1, v1, pooled);
    kB<<<1200, 256, 0, stream>>>(pooled, fc1_w, fc1_b, g2, b2, m2, v2,
                                 fc2_w, sp);
    kC<<<128, 64, 0, stream>>>(sp, fc2_b, g3, b3, m3, v3, fw, fb, out);
}

// Round 18
// 172.968 us; speedup vs baseline: 1.0264x; 1.0264x over previous
//
#include <hip/hip_runtime.h>
#include <math.h>

// ExplaiNN fused forward: B=128, N=300, L=600, K=19, C1=100, PS=7
// LC=582, LP=83, NC=2
// FINAL (R16-exact best config, 173.6us):
//   fills ~90us (harness ws re-poison @ 74% HBM peak -- its own roofline)
//   kA ~45us   (58% of fp32-issue roofline; 7 latency interventions falsified)
//   kB ~12us, kP+kC ~5us, launch gaps ~20us
#define EPS_ 1e-5f

// ---------------------------------------------------------------------------
// kP: cw4[c][kq][n][0..3] float4 conv-weight pack for kA (20 blocks, ~2us).
// ---------------------------------------------------------------------------
__global__ __launch_bounds__(256) void kP(const float* __restrict__ conv_w,
                                          float* __restrict__ cw4) {
    const int cq = blockIdx.x;              // 0..19
    const int c  = cq / 5;
    const int kq = cq - c * 5;
    for (int n = threadIdx.x; n < 300; n += 256) {
        float4 v;
        const int k0 = 4 * kq;
        v.x = (k0 + 0 < 19) ? conv_w[n * 76 + c * 19 + k0 + 0] : 0.f;
        v.y = (k0 + 1 < 19) ? conv_w[n * 76 + c * 19 + k0 + 1] : 0.f;
        v.z = (k0 + 2 < 19) ? conv_w[n * 76 + c * 19 + k0 + 2] : 0.f;
        v.w = (k0 + 3 < 19) ? conv_w[n * 76 + c * 19 + k0 + 3] : 0.f;
        reinterpret_cast<float4*>(cw4)[(c * 5 + kq) * 300 + n] = v;
    }
}

// ---------------------------------------------------------------------------
// kA: conv1d(4ch,K=19) + bias + bn1 + exp + maxpool(7,7).  R9/R16-exact
// (best band 44-47.5us across 3 identical-code runs; VGPR=32, VALUBusy
// ~58-62%). Loop-interchanged persistent acc[4p x 7q]; cw4 float4 weight
// loads (20/task, 112 FMAs each); x window wave-uniform -> s_loads.
// grid 128*112 x 64: id = b*112+sub (112%8==0 -> same-XCD pooled lines).
// Falsified alternatives: 4-wave WGs (R8 ↓), 6-wide tile (R13 ↓), lane=b
// (R3-5 ↓), L1-pin remap (R17 =), fp16-MFMA im2col (R15 ↓, marshalling).
// ---------------------------------------------------------------------------
__global__ __launch_bounds__(64) void kA(
        const float* __restrict__ x,        // [128][4][600]
        const float* __restrict__ cw4,      // [4][5][300][4]
        const float* __restrict__ conv_b,
        const float* __restrict__ g1, const float* __restrict__ b1,
        const float* __restrict__ m1, const float* __restrict__ v1,
        float* __restrict__ pooled)         // [300][83][128]
{
    const int id  = blockIdx.x;             // b*112 + sub
    const int b   = id / 112;
    const int sub = id - b * 112;
    if (sub >= 105) return;
    const int ng  = sub / 21;
    const int pc  = sub - ng * 21;
    const int p0c = pc * 4;
    const int p0  = (p0c > 79) ? 79 : p0c;  // p=79 done twice, same value
    const int lane = threadIdx.x;
    const int n   = ng * 64 + lane;
    const int nc  = (n < 300) ? n : 299;

    const float4* w4 = reinterpret_cast<const float4*>(cw4);

    float acc[28];
    #pragma unroll
    for (int i = 0; i < 28; ++i) acc[i] = 0.f;

    #pragma unroll 1
    for (int c = 0; c < 4; ++c) {
        const float* xc = x + b * 2400 + c * 600 + 7 * p0;  // uniform -> s_load
        float xw[46];
        #pragma unroll
        for (int j = 0; j < 46; ++j) xw[j] = xc[j];
        #pragma unroll
        for (int kq = 0; kq < 5; ++kq) {
            const float4 wv = w4[(c * 5 + kq) * 300 + nc];  // 4 k's, coalesced
            const int ni = (kq == 4) ? 3 : 4;               // k<19
            #pragma unroll
            for (int i = 0; i < ni; ++i) {
                const int k = 4 * kq + i;
                const float wvv = (i == 0) ? wv.x : (i == 1) ? wv.y
                                : (i == 2) ? wv.z : wv.w;
                #pragma unroll
                for (int p = 0; p < 4; ++p)
                    #pragma unroll
                    for (int q = 0; q < 7; ++q)
                        acc[p * 7 + q] = fmaf(xw[7 * p + q + k], wvv,
                                              acc[p * 7 + q]);
            }
        }
    }

    const float A1 = g1[nc] * rsqrtf(v1[nc] + EPS_);
    const float B1 = fmaf(A1, conv_b[nc] - m1[nc], b1[nc]);
    if (n < 300) {
        float* op = pooled + ((size_t)n * 83 + p0) * 128 + b;
        #pragma unroll
        for (int p = 0; p < 4; ++p) {
            float mx = -INFINITY;           // exp monotone: max before exp
            #pragma unroll
            for (int q = 0; q < 7; ++q)
                mx = fmaxf(mx, fmaf(A1, acc[p * 7 + q], B1));
            op[p * 128] = __expf(mx);
        }
    }
}

// ---------------------------------------------------------------------------
// kB: fc1(K=83) + bn2 + relu + fc2 partial.  R16-exact (passed, ~12us):
// block = (n, b-half, h-half), grid 1200 x 256 -> 4.7 waves/SIMD;
// sW[83][60] staging (8-way writes ~free, broadcast reads conflict-free);
// fc2 partials to sp; kC absorbs fc2b+bn3+relu.
// ---------------------------------------------------------------------------
__global__ __launch_bounds__(256) void kB(
        const float* __restrict__ pooled,   // [300][83][128]
        const float* __restrict__ fc1w,     // [300][100][83]
        const float* __restrict__ fc1b,     // [300][100]
        const float* __restrict__ g2, const float* __restrict__ b2,
        const float* __restrict__ m2, const float* __restrict__ v2,
        const float* __restrict__ fc2w,     // [300][100]
        float* __restrict__ sp)             // [2][300][128] fc2 partials
{
    __shared__ float sW[83 * 60];           // 19.9 KB
    __shared__ float sRed[4][64];
    const int id  = blockIdx.x;             // 0..1199
    const int n   = id >> 2;
    const int rem = id & 3;
    const int bh  = rem >> 1;
    const int hq  = rem & 1;                // h-half: h in [hq*50, hq*50+50)
    const int tid = threadIdx.x;

    {   // stage this h-half: coalesced reads; stride-60 writes (8-way, ~free)
        const float* src = fc1w + (size_t)n * 8300 + hq * 50 * 83;
        for (int i = tid; i < 4150; i += 256) {
            const int h = i / 83, p = i - h * 83;
            sW[p * 60 + h] = src[i];
        }
        for (int i = tid; i < 830; i += 256) {   // zero pad h'=50..59
            const int p = i / 10, h = 50 + (i - p * 10);
            sW[p * 60 + h] = 0.f;
        }
    }
    __syncthreads();

    const int lane = tid & 63;
    const int wv   = __builtin_amdgcn_readfirstlane(tid >> 6);  // 0..3
    const int h0   = wv * 13;               // local: 0,13,26,39
    const int nh   = (wv < 3) ? 13 : 11;    // 13*3+11 = 50
    const int bb   = bh * 64 + lane;

    const float* pp = pooled + (size_t)n * 83 * 128 + bb;

    float acc[13];
    #pragma unroll
    for (int j = 0; j < 13; ++j) acc[j] = 0.f;

    #pragma unroll 4
    for (int p = 0; p < 83; ++p) {
        const float pv = pp[p * 128];       // coalesced 256B
        const float* wrow = sW + p * 60 + h0;
        #pragma unroll
        for (int j = 0; j < 13; ++j)        // broadcast b32 reads
            acc[j] = fmaf(wrow[j], pv, acc[j]);
    }

    // bn2 + relu + fc2 partial over this wave's real h's (params uniform)
    const int hbase = n * 100 + hq * 50 + h0;
    float part = 0.f;
    for (int j = 0; j < nh; ++j) {
        const int hi = hbase + j;
        const float A2 = g2[hi] * rsqrtf(v2[hi] + EPS_);
        const float C2 = fmaf(A2, fc1b[hi] - m2[hi], b2[hi]);
        part = fmaf(fmaxf(fmaf(A2, acc[j], C2), 0.f), fc2w[hi], part);
    }
    sRed[wv][lane] = part;
    __syncthreads();

    if (tid < 64) {
        const float s = sRed[0][tid] + sRed[1][tid] + sRed[2][tid] + sRed[3][tid];
        sp[((size_t)hq * 300 + n) * 128 + bh * 64 + tid] = s;
    }
}

// ---------------------------------------------------------------------------
// kC: combine fc2 partials + fc2b + bn3 + relu, then final [300]x[2] matmul.
// ---------------------------------------------------------------------------
__global__ __launch_bounds__(64) void kC(
        const float* __restrict__ sp,       // [2][300][128]
        const float* __restrict__ fc2b,
        const float* __restrict__ g3, const float* __restrict__ b3,
        const float* __restrict__ m3, const float* __restrict__ v3,
        const float* __restrict__ fw,       // [2][300]
        const float* __restrict__ fb,
        float* __restrict__ out)            // [128][2]
{
    const int b = blockIdx.x, t = threadIdx.x;
    float a0 = 0.f, a1 = 0.f;
    for (int nn = t; nn < 300; nn += 64) {
        const float s = sp[nn * 128 + b] + sp[(300 + nn) * 128 + b] + fc2b[nn];
        const float A3 = g3[nn] * rsqrtf(v3[nn] + EPS_);
        const float z = fmaxf(fmaf(A3, s - m3[nn], b3[nn]), 0.f);
        a0 = fmaf(z, fw[nn], a0);
        a1 = fmaf(z, fw[300 + nn], a1);
    }
    #pragma unroll
    for (int off = 32; off > 0; off >>= 1) {
        a0 += __shfl_xor(a0, off, 64);
        a1 += __shfl_xor(a1, off, 64);
    }
    if (t == 0) {
        out[b * 2 + 0] = a0 + fb[0];
        out[b * 2 + 1] = a1 + fb[1];
    }
}

extern "C" void kernel_launch(void* const* d_in, const int* in_sizes, int n_in,
                              void* d_out, int out_size, void* d_ws, size_t ws_size,
                              hipStream_t stream) {
    const float* x      = (const float*)d_in[0];
    const float* conv_w = (const float*)d_in[1];
    const float* conv_b = (const float*)d_in[2];
    const float* g1 = (const float*)d_in[3];
    const float* b1 = (const float*)d_in[4];
    const float* m1 = (const float*)d_in[5];
    const float* v1 = (const float*)d_in[6];
    const float* fc1_w = (const float*)d_in[7];
    const float* fc1_b = (const float*)d_in[8];
    const float* g2 = (const float*)d_in[9];
    const float* b2 = (const float*)d_in[10];
    const float* m2 = (const float*)d_in[11];
    const float* v2 = (const float*)d_in[12];
    const float* fc2_w = (const float*)d_in[13];
    const float* fc2_b = (const float*)d_in[14];
    const float* g3 = (const float*)d_in[15];
    const float* b3 = (const float*)d_in[16];
    const float* m3 = (const float*)d_in[17];
    const float* v3 = (const float*)d_in[18];
    const float* fw = (const float*)d_in[19];
    const float* fb = (const float*)d_in[20];
    float* out = (float*)d_out;

    float* pooled = (float*)d_ws;                        // 300*83*128 = 3187200
    float* sp     = pooled + (size_t)300 * 83 * 128;     // 2*300*128  = 76800
    float* cw4    = sp + 76800;                          // 4*5*300*4  = 24000
    // total ws: ~13.2 MB

    kP<<<20, 256, 0, stream>>>(conv_w, cw4);
    kA<<<128 * 112, 64, 0, stream>>>(x, cw4, conv_b, g1, b1, m1, v1, pooled);
    kB<<<1200, 256, 0, stream>>>(pooled, fc1_w, fc1_b, g2, b2, m2, v2,
                                 fc2_w, sp);
    kC<<<128, 64, 0, stream>>>(sp, fc2_b, g3, b3, m3, v3, fw, fb, out);
}